// Round 6
// baseline (187.251 us; speedup 1.0000x reference)
//
#include <hip/hip_runtime.h>
#include <hip/hip_bf16.h>
#include <math.h>

#define BB 4
#define CC 64
#define HH 160
#define WW 160
#define HWs (HH*WW)        // 25600
#define NPIX (BB*HWs)      // 102400

using bf16 = __hip_bfloat16;
typedef __attribute__((ext_vector_type(8)))  short short8v;    // 8 x bf16 bits
typedef __attribute__((ext_vector_type(16))) float float16v;   // 32x32 MFMA acc

__device__ __forceinline__ unsigned short f2bfu(float f){
    union { bf16 h; unsigned short u; } cv; cv.h = __float2bfloat16(f); return cv.u;
}
__device__ __forceinline__ float bfu2f(unsigned short u){
    union { float f; unsigned int i; } cv; cv.i = ((unsigned int)u)<<16; return cv.f;
}
__device__ __forceinline__ float16v fzero16(){
    float16v z;
    #pragma unroll
    for(int i=0;i<16;i++) z[i]=0.f;
    return z;
}

// ---- workspace layout (float offsets) ----
// All MFMA frags are 32x32x16: A[m=lane&31][k=(lane>>5)*8+j]; D col=lane&31,
// row=(r&3)+8*(r>>2)+4*(lane>>5)
constexpr int B1X1 = 0;        // 64   : summed dyn1d biases (fp32)
constexpr int SFBo = 64;       // 64   : BN-folded sf bias (fp32)
constexpr int SFWf = 128;      // 18432 fl = 36864 bf16 : sf A-frags [og][tap*4+kc][lane][j]
constexpr int BAWf = 18560;    // 9216 fl = 18432 bf16  : ba_w1 A-frags [tap*4+kc][lane][j]
constexpr int FUWf = 27776;    // 2048 fl = 4096 bf16   : dyn1d A-frags [og][kc][lane][j]
constexpr int FCWf = 29824;    // 2048 fl = 4096 bf16   : fc A-frags [og][kc][lane][j]
constexpr int WS_FLOATS = 31872;   // 127,488 B
// bf16 NHWC region after: XB [p][c], NPIX*64 elems (13.1 MB). FUS now lives in LDS (R5 merge).

// ================= K0: weight prep (folds + 32x32 MFMA packs) — R1 verbatim =================
__global__ void k_prep(const float* __restrict__ rk5w, const float* __restrict__ rk5b,
                       const float* __restrict__ rk7w, const float* __restrict__ rk7b,
                       const float* __restrict__ lk5w, const float* __restrict__ lk5b,
                       const float* __restrict__ lk7w, const float* __restrict__ lk7b,
                       const float* __restrict__ sfw,  const float* __restrict__ sfb,
                       const float* __restrict__ bng,  const float* __restrict__ bnb,
                       const float* __restrict__ bnm,  const float* __restrict__ bnv,
                       const float* __restrict__ baw1, const float* __restrict__ fcw,
                       float* __restrict__ ws)
{
    int tid = blockIdx.x*blockDim.x + threadIdx.x;
    int nt  = gridDim.x*blockDim.x;
    for(int o=tid;o<64;o+=nt){
        int grp=o>>4, oo=o&15; int K=(grp&1)?7:5;
        const float* bp = (grp==0)?rk5b:(grp==1)?rk7b:(grp==2)?lk5b:lk7b;
        float s=0.f; for(int k=0;k<K;k++) s += bp[oo*K+k];
        ws[B1X1+o]=s;
    }
    for(int oc=tid;oc<64;oc+=nt){
        float sc = bng[oc]*rsqrtf(bnv[oc]+1e-5f);
        ws[SFBo+oc] = sfb[oc]*sc + bnb[oc] - bnm[oc]*sc;
    }
    unsigned short* sfwf = (unsigned short*)(ws + SFWf);
    for(int idx=tid; idx<36864; idx+=nt){
        int og = idx/18432;  int rem = idx - og*18432;
        int f  = rem>>9;     int r2 = rem & 511;
        int lane = r2>>3;    int j = r2&7;
        int tap = f>>2, kc = f&3;
        int oc = og*32 + (lane&31);
        int ic = kc*16 + (lane>>5)*8 + j;
        float sc = bng[oc]*rsqrtf(bnv[oc]+1e-5f);
        sfwf[idx] = f2bfu(sfw[(oc*64+ic)*9 + tap] * sc);
    }
    unsigned short* bawf = (unsigned short*)(ws + BAWf);
    for(int idx=tid; idx<18432; idx+=nt){
        int f  = idx>>9;     int r2 = idx & 511;
        int lane = r2>>3;    int j = r2&7;
        int tap = f>>2, kc = f&3;
        int oc = lane&31;
        int ic = kc*16 + (lane>>5)*8 + j;
        bawf[idx] = f2bfu(baw1[(oc*64+ic)*9 + tap]);
    }
    unsigned short* fuwf = (unsigned short*)(ws + FUWf);
    for(int idx=tid; idx<4096; idx+=nt){
        int og   = idx>>11;
        int kc   = (idx>>9)&3;
        int lane = (idx>>3)&63;
        int j    = idx&7;
        int oc = og*32 + (lane&31);
        int c  = kc*16 + (lane>>5)*8 + j;
        int grp = oc>>4, oo = oc&15; int K = (grp&1)?7:5;
        const float* w = (grp==0)?rk5w:(grp==1)?rk7w:(grp==2)?lk5w:lk7w;
        float s = 0.f;
        for(int k=0;k<K;k++) s += w[(oo*K+k)*64 + c];
        fuwf[idx] = f2bfu(s);
    }
    unsigned short* fcwf = (unsigned short*)(ws + FCWf);
    for(int idx=tid; idx<4096; idx+=nt){
        int og   = idx>>11;
        int kc   = (idx>>9)&3;
        int lane = (idx>>3)&63;
        int j    = idx&7;
        int oc = og*32 + (lane&31);
        int c  = kc*16 + (lane>>5)*8 + j;
        fcwf[idx] = f2bfu(fcw[oc*64 + c]);
    }
}

// ============ K1: x (fp32 NCHW) -> XB (bf16 NHWC) — R1 verbatim ============
__global__ __launch_bounds__(256)
void k_x2nhwc(const float* __restrict__ x, unsigned short* __restrict__ xb)
{
    __shared__ unsigned short ls[128*72];
    const int t = threadIdx.x;
    const int p0 = blockIdx.x*128;
    const int b = p0 / HWs, pp0 = p0 % HWs;
    const float4* xb4 = (const float4*)(x + (size_t)b*CC*HWs + pp0);
    #pragma unroll
    for(int iter=0; iter<8; iter++){
        int idx = iter*256 + t;
        int c = idx>>5, g = idx&31;          // 64 ch x 32 float4-groups
        float4 v = xb4[(size_t)c*(HWs/4) + g];
        int px = g*4;
        int bs = (c>>3) ^ ((g>>1)&7);        // same swizzle for px..px+3
        unsigned short* base = ls + bs*8 + (c&7);
        base[(px+0)*72] = f2bfu(v.x);
        base[(px+1)*72] = f2bfu(v.y);
        base[(px+2)*72] = f2bfu(v.z);
        base[(px+3)*72] = f2bfu(v.w);
    }
    __syncthreads();
    #pragma unroll
    for(int iter=0; iter<4; iter++){
        int idx = iter*256 + t;
        int sub = idx&7, px = idx>>3;
        int bs = sub ^ ((px>>3)&7);
        short8v v = *(short8v*)(ls + px*72 + bs*8);
        *(short8v*)(xb + ((size_t)(p0+px))*64 + sub*8) = v;
    }
}

// ====== K2 (R5 merge): fuseA on 18x10 halo (FUS kept in LDS) + fuseB + residual ======
// x-tile 20x12 (halo 2), FUS tile 18x10 (halo 1), output 16x8. 4 waves.
// fuseA-ext: 6 MFMA px-tiles of 32; wave w does tiles {w} and {w+4|w<2}.
// OOB FUS pixels are exactly 0 (sx=0, a=0 -> P=Q=0), matching zero-padding.
__global__ __launch_bounds__(256)
void k_fuse(const unsigned short* __restrict__ xb, const float* __restrict__ bab1,
            const float* __restrict__ baw2, const float* __restrict__ bab2,
            const float* __restrict__ ws, const float* __restrict__ fcb,
            const float* __restrict__ x, float* __restrict__ out)
{
    __shared__ unsigned short xt[240*72];     // 34,560 B : x  [12 rows][20 cols] pad-72
    __shared__ unsigned short ftile[180*72];  // 25,920 B : FUS [10 rows][18 cols] pad-72
    __shared__ float ebuf[2][180];            //  1,440 B
    const int bw = blockIdx.x, bh = blockIdx.y, b = blockIdx.z;
    const int t = threadIdx.x;
    const int wave = t>>6, lane = t&63;
    const int half = lane>>5, n = lane&31;
    const int w0 = bw*16, h0 = bh*8;

    // --- stage x tile (halo 2) from XB, zero-filled OOB ---
    const unsigned short* fb = xb + (size_t)b*HWs*64;
    for(int idx=t; idx<1920; idx+=256){
        int sub = idx&7; int pix = idx>>3;
        int r = pix/20, c = pix - r*20;
        int gh = h0-2+r, gw = w0-2+c;
        short8v v = {0,0,0,0,0,0,0,0};
        if(gh>=0&&gh<HH&&gw>=0&&gw<WW)
            v = *(const short8v*)(fb + ((size_t)(gh*WW+gw))*64 + sub*8);
        *(short8v*)(xt + pix*72 + sub*8) = v;
    }
    __syncthreads();

    // --- phase B: attn conv + colsum for this wave's px-tiles (results in regs) ---
    float czr[2], sxr[2];
    const unsigned short* bawf = (const unsigned short*)(ws + BAWf);
    #pragma unroll
    for(int rep=0; rep<2; rep++){
        int g = wave + rep*4;
        if(g < 6){
            int p = g*32 + n; if(p > 179) p = 179;
            int pr = p/18, pc = p - pr*18;
            float16v acc = fzero16();
            #pragma unroll
            for(int kc=0; kc<4; kc++){
                short8v af[9];
                #pragma unroll
                for(int tap=0; tap<9; tap++)
                    af[tap] = *(const short8v*)(bawf + (((size_t)(tap*4+kc))*64 + lane)*8);
                #pragma unroll
                for(int tap=0; tap<9; tap++){
                    const int dh = tap/3, dw = tap%3;
                    short8v bf = *(const short8v*)(xt + ((pr+dh)*20 + pc+dw)*72
                                                   + kc*16 + half*8);
                    acc = __builtin_amdgcn_mfma_f32_32x32x16_bf16(af[tap], bf, acc, 0,0,0);
                }
            }
            float cz = 0.f;
            #pragma unroll
            for(int r=0;r<16;r++){
                int oc = (r&3) + 8*(r>>2) + 4*half;
                cz += fmaxf(acc[r]+bab1[oc],0.f)*baw2[oc];
            }
            cz += __shfl_xor(cz, 32);
            czr[rep] = cz;
            // channel sum via ones-A MFMA at the center pixel
            short8v ones;
            #pragma unroll
            for(int j=0;j<8;j++) ones[j] = (short)0x3F80;
            float16v s = fzero16();
            #pragma unroll
            for(int kc=0; kc<4; kc++){
                short8v bf = *(const short8v*)(xt + ((pr+1)*20 + pc+1)*72 + kc*16 + half*8);
                s = __builtin_amdgcn_mfma_f32_32x32x16_bf16(ones, bf, s, 0,0,0);
            }
            sxr[rep] = s[0];
        }
    }

    // --- phase C: Sobel for all 180 FUS px (2 channel-halves each) ---
    for(int idx=t; idx<360; idx+=256){
        const int hf = (idx>=180) ? 1 : 0;
        const int px2 = idx - hf*180;
        const int r = px2/18, c = px2 - (px2/18)*18;
        float e = 0.f;
        #pragma unroll
        for(int s=0; s<4; s++){
            const int sub = hf*4 + s;
            if(hf==0){
                short8v a0 = *(const short8v*)(xt + ((r  )*20 + c  )*72 + sub*8);
                short8v a2 = *(const short8v*)(xt + ((r  )*20 + c+2)*72 + sub*8);
                short8v a3 = *(const short8v*)(xt + ((r+1)*20 + c  )*72 + sub*8);
                short8v a5 = *(const short8v*)(xt + ((r+1)*20 + c+2)*72 + sub*8);
                short8v a6 = *(const short8v*)(xt + ((r+2)*20 + c  )*72 + sub*8);
                short8v a8 = *(const short8v*)(xt + ((r+2)*20 + c+2)*72 + sub*8);
                #pragma unroll
                for(int j=0;j<8;j++){
                    float gx = (bfu2f((unsigned short)a2[j]) - bfu2f((unsigned short)a0[j]))
                       + 2.f*(bfu2f((unsigned short)a5[j]) - bfu2f((unsigned short)a3[j]))
                       +      (bfu2f((unsigned short)a8[j]) - bfu2f((unsigned short)a6[j]));
                    e += fabsf(gx);
                }
            } else {
                short8v b0 = *(const short8v*)(xt + ((r  )*20 + c  )*72 + sub*8);
                short8v b1 = *(const short8v*)(xt + ((r  )*20 + c+1)*72 + sub*8);
                short8v b2 = *(const short8v*)(xt + ((r  )*20 + c+2)*72 + sub*8);
                short8v b6 = *(const short8v*)(xt + ((r+2)*20 + c  )*72 + sub*8);
                short8v b7 = *(const short8v*)(xt + ((r+2)*20 + c+1)*72 + sub*8);
                short8v b8 = *(const short8v*)(xt + ((r+2)*20 + c+2)*72 + sub*8);
                #pragma unroll
                for(int j=0;j<8;j++){
                    float gy = (bfu2f((unsigned short)b6[j]) - bfu2f((unsigned short)b0[j]))
                       + 2.f*(bfu2f((unsigned short)b7[j]) - bfu2f((unsigned short)b1[j]))
                       +      (bfu2f((unsigned short)b8[j]) - bfu2f((unsigned short)b2[j]));
                    e += fabsf(gy);
                }
            }
        }
        ebuf[hf][px2] = e;
    }
    __syncthreads();

    // --- phase D: sigmoid scalars + dyn1d -> FUS values written into LDS ftile ---
    const unsigned short* fuwf = (const unsigned short*)(ws + FUWf);
    #pragma unroll
    for(int rep=0; rep<2; rep++){
        int g = wave + rep*4;
        if(g < 6){
            int p0g = g*32 + n;
            bool wr = (p0g < 180);
            int p = wr ? p0g : 179;
            int pr = p/18, pc = p - pr*18;
            float z = czr[rep] + bab2[0] + (ebuf[0][p] + ebuf[1][p]) * (1.f/32.f);
            float A = 1.f + 1.f/(1.f+__expf(-z));
            float Q = A * sxr[rep];
            float P = A * Q;
            #pragma unroll
            for(int og=0; og<2; og++){
                float16v a = fzero16();
                #pragma unroll
                for(int kc=0; kc<4; kc++){
                    short8v wf = *(const short8v*)(fuwf + (((size_t)og*4 + kc)*64 + lane)*8);
                    short8v bf = *(const short8v*)(xt + ((pr+1)*20 + pc+1)*72 + kc*16 + half*8);
                    a = __builtin_amdgcn_mfma_f32_32x32x16_bf16(wf, bf, a, 0,0,0);
                }
                float bq[16];
                #pragma unroll
                for(int r=0;r<16;r++) bq[r] = ws[B1X1 + og*32 + (r&3)+8*(r>>2)+4*half];
                unsigned short* base = ftile + p*72 + og*32 + 4*half;
                #pragma unroll
                for(int gq=0; gq<4; gq++){
                    union { unsigned long long u; unsigned short s[4]; } pk;
                    #pragma unroll
                    for(int rr=0; rr<4; rr++)
                        pk.s[rr] = f2bfu(P*a[4*gq+rr] + Q*bq[4*gq+rr]);
                    if(wr) *(unsigned long long*)(base + 8*gq) = pk.u;
                }
            }
        }
    }
    __syncthreads();

    // --- phase E: sf 3x3 conv + ReLU + fc 1x1 + residual (R1 fuseB body, LDS source) ---
    const int row = 2*wave + (n>>4), col = n&15;
    const unsigned short* sfwf = (const unsigned short*)(ws + SFWf);
    const unsigned short* fcwf = (const unsigned short*)(ws + FCWf);
    float16v F0 = fzero16(), F1 = fzero16();

    #pragma unroll
    for(int og=0; og<2; og++){             // sf output group = fc input group
        float16v Y = fzero16();
        #pragma unroll
        for(int kc=0; kc<4; kc++){
            short8v af[9];
            #pragma unroll
            for(int tap=0; tap<9; tap++)
                af[tap] = *(const short8v*)(sfwf + (((size_t)og*36 + tap*4+kc)*64 + lane)*8);
            #pragma unroll
            for(int tap=0; tap<9; tap++){
                const int dh = tap/3, dw = tap%3;
                short8v bf = *(const short8v*)(ftile + ((row+dh)*18 + col+dw)*72
                                               + kc*16 + half*8);
                Y = __builtin_amdgcn_mfma_f32_32x32x16_bf16(af[tap], bf, Y, 0,0,0);
            }
        }
        unsigned short yb[16];
        #pragma unroll
        for(int r=0;r<16;r++){
            float bias = ws[SFBo + og*32 + (r&3)+8*(r>>2)+4*half];
            yb[r] = f2bfu(fmaxf(Y[r] + bias, 0.f));
        }
        #pragma unroll
        for(int kcl=0; kcl<2; kcl++){
            const int kc_fc = 2*og + kcl;
            unsigned short l0,l1,l2,l3, s0,s1,s2,s3;
            if(half==0){ l0=yb[8*kcl+0]; l1=yb[8*kcl+1]; l2=yb[8*kcl+2]; l3=yb[8*kcl+3];
                         s0=yb[8*kcl+4]; s1=yb[8*kcl+5]; s2=yb[8*kcl+6]; s3=yb[8*kcl+7]; }
            else       { l0=yb[8*kcl+4]; l1=yb[8*kcl+5]; l2=yb[8*kcl+6]; l3=yb[8*kcl+7];
                         s0=yb[8*kcl+0]; s1=yb[8*kcl+1]; s2=yb[8*kcl+2]; s3=yb[8*kcl+3]; }
            int p0 = (int)((unsigned)s0 | ((unsigned)s1<<16));
            int p1 = (int)((unsigned)s2 | ((unsigned)s3<<16));
            int r0 = __shfl_xor(p0, 32);
            int r1 = __shfl_xor(p1, 32);
            unsigned short m0 = (unsigned short)(r0 & 0xffff);
            unsigned short m1 = (unsigned short)(((unsigned)r0) >> 16);
            unsigned short m2 = (unsigned short)(r1 & 0xffff);
            unsigned short m3 = (unsigned short)(((unsigned)r1) >> 16);
            short8v B;
            if(half==0){ B[0]=(short)l0; B[1]=(short)l1; B[2]=(short)l2; B[3]=(short)l3;
                         B[4]=(short)m0; B[5]=(short)m1; B[6]=(short)m2; B[7]=(short)m3; }
            else       { B[0]=(short)m0; B[1]=(short)m1; B[2]=(short)m2; B[3]=(short)m3;
                         B[4]=(short)l0; B[5]=(short)l1; B[6]=(short)l2; B[7]=(short)l3; }
            short8v fa0 = *(const short8v*)(fcwf + (((size_t)0*4 + kc_fc)*64 + lane)*8);
            short8v fa1 = *(const short8v*)(fcwf + (((size_t)1*4 + kc_fc)*64 + lane)*8);
            F0 = __builtin_amdgcn_mfma_f32_32x32x16_bf16(fa0, B, F0, 0,0,0);
            F1 = __builtin_amdgcn_mfma_f32_32x32x16_bf16(fa1, B, F1, 0,0,0);
        }
    }
    // --- epilogue: bias + residual -> fp32 NCHW out ---
    #pragma unroll
    for(int og=0; og<2; og++){
        #pragma unroll
        for(int r=0;r<16;r++){
            int oc = og*32 + (r&3)+8*(r>>2)+4*half;
            size_t g = ((size_t)(b*CC + oc))*HWs + (h0+row)*WW + w0 + col;
            float v = (og==0) ? F0[r] : F1[r];
            out[g] = v + fcb[oc] + x[g];
        }
    }
}

extern "C" void kernel_launch(void* const* d_in, const int* in_sizes, int n_in,
                              void* d_out, int out_size, void* d_ws, size_t ws_size,
                              hipStream_t stream)
{
    const float* x     = (const float*)d_in[0];
    const float* ba_w1 = (const float*)d_in[1];
    const float* ba_b1 = (const float*)d_in[2];
    const float* ba_w2 = (const float*)d_in[3];
    const float* ba_b2 = (const float*)d_in[4];
    // d_in[5..12] = offset branch: dead code in the reference (never reaches the output)
    const float* rk5_w = (const float*)d_in[13];
    const float* rk5_b = (const float*)d_in[14];
    const float* rk7_w = (const float*)d_in[15];
    const float* rk7_b = (const float*)d_in[16];
    const float* lk5_w = (const float*)d_in[17];
    const float* lk5_b = (const float*)d_in[18];
    const float* lk7_w = (const float*)d_in[19];
    const float* lk7_b = (const float*)d_in[20];
    const float* sf_w  = (const float*)d_in[21];
    const float* sf_b  = (const float*)d_in[22];
    const float* bng   = (const float*)d_in[23];
    const float* bnb   = (const float*)d_in[24];
    const float* bnm   = (const float*)d_in[25];
    const float* bnv   = (const float*)d_in[26];
    const float* fc_w  = (const float*)d_in[27];
    const float* fc_b  = (const float*)d_in[28];

    float* wsf = (float*)d_ws;
    unsigned short* XB  = (unsigned short*)((char*)d_ws + (size_t)WS_FLOATS*4);
    float* out = (float*)d_out;

    k_prep<<<64, 256, 0, stream>>>(rk5_w,rk5_b,rk7_w,rk7_b,lk5_w,lk5_b,lk7_w,lk7_b,
                                   sf_w,sf_b,bng,bnb,bnm,bnv, ba_w1, fc_w, wsf);
    k_x2nhwc<<<NPIX/128, 256, 0, stream>>>(x, XB);
    k_fuse<<<dim3(10,20,4), 256, 0, stream>>>(XB, ba_b1, ba_w2, ba_b2, wsf, fc_b, x, out);
}

// Round 7
// 173.960 us; speedup vs baseline: 1.0764x; 1.0764x over previous
//
#include <hip/hip_runtime.h>
#include <hip/hip_bf16.h>
#include <math.h>

#define BB 4
#define CC 64
#define HH 160
#define WW 160
#define HWs (HH*WW)        // 25600
#define NPIX (BB*HWs)      // 102400

using bf16 = __hip_bfloat16;
typedef __attribute__((ext_vector_type(8)))  short short8v;    // 8 x bf16 bits
typedef __attribute__((ext_vector_type(16))) float float16v;   // 32x32 MFMA acc

__device__ __forceinline__ unsigned short f2bfu(float f){
    union { bf16 h; unsigned short u; } cv; cv.h = __float2bfloat16(f); return cv.u;
}
__device__ __forceinline__ float bfu2f(unsigned short u){
    union { float f; unsigned int i; } cv; cv.i = ((unsigned int)u)<<16; return cv.f;
}
__device__ __forceinline__ float16v fzero16(){
    float16v z;
    #pragma unroll
    for(int i=0;i<16;i++) z[i]=0.f;
    return z;
}

// ---- workspace layout (float offsets) ----
constexpr int B1X1 = 0;        // 64   : summed dyn1d biases (fp32)
constexpr int SFBo = 64;       // 64   : BN-folded sf bias (fp32)
constexpr int SFWf = 128;      // sf A-frags [og][tap*4+kc][lane][j]
constexpr int BAWf = 18560;    // ba_w1 A-frags [tap*4+kc][lane][j]
constexpr int FUWf = 27776;    // dyn1d A-frags [og][kc][lane][j]
constexpr int FCWf = 29824;    // fc A-frags [og][kc][lane][j]
constexpr int WS_FLOATS = 31872;
// bf16 NHWC region after: XB [p][c], NPIX*64 elems (13.1 MB). FUS lives in LDS.

// ================= K0: weight prep — R1 verbatim =================
__global__ void k_prep(const float* __restrict__ rk5w, const float* __restrict__ rk5b,
                       const float* __restrict__ rk7w, const float* __restrict__ rk7b,
                       const float* __restrict__ lk5w, const float* __restrict__ lk5b,
                       const float* __restrict__ lk7w, const float* __restrict__ lk7b,
                       const float* __restrict__ sfw,  const float* __restrict__ sfb,
                       const float* __restrict__ bng,  const float* __restrict__ bnb,
                       const float* __restrict__ bnm,  const float* __restrict__ bnv,
                       const float* __restrict__ baw1, const float* __restrict__ fcw,
                       float* __restrict__ ws)
{
    int tid = blockIdx.x*blockDim.x + threadIdx.x;
    int nt  = gridDim.x*blockDim.x;
    for(int o=tid;o<64;o+=nt){
        int grp=o>>4, oo=o&15; int K=(grp&1)?7:5;
        const float* bp = (grp==0)?rk5b:(grp==1)?rk7b:(grp==2)?lk5b:lk7b;
        float s=0.f; for(int k=0;k<K;k++) s += bp[oo*K+k];
        ws[B1X1+o]=s;
    }
    for(int oc=tid;oc<64;oc+=nt){
        float sc = bng[oc]*rsqrtf(bnv[oc]+1e-5f);
        ws[SFBo+oc] = sfb[oc]*sc + bnb[oc] - bnm[oc]*sc;
    }
    unsigned short* sfwf = (unsigned short*)(ws + SFWf);
    for(int idx=tid; idx<36864; idx+=nt){
        int og = idx/18432;  int rem = idx - og*18432;
        int f  = rem>>9;     int r2 = rem & 511;
        int lane = r2>>3;    int j = r2&7;
        int tap = f>>2, kc = f&3;
        int oc = og*32 + (lane&31);
        int ic = kc*16 + (lane>>5)*8 + j;
        float sc = bng[oc]*rsqrtf(bnv[oc]+1e-5f);
        sfwf[idx] = f2bfu(sfw[(oc*64+ic)*9 + tap] * sc);
    }
    unsigned short* bawf = (unsigned short*)(ws + BAWf);
    for(int idx=tid; idx<18432; idx+=nt){
        int f  = idx>>9;     int r2 = idx & 511;
        int lane = r2>>3;    int j = r2&7;
        int tap = f>>2, kc = f&3;
        int oc = lane&31;
        int ic = kc*16 + (lane>>5)*8 + j;
        bawf[idx] = f2bfu(baw1[(oc*64+ic)*9 + tap]);
    }
    unsigned short* fuwf = (unsigned short*)(ws + FUWf);
    for(int idx=tid; idx<4096; idx+=nt){
        int og   = idx>>11;
        int kc   = (idx>>9)&3;
        int lane = (idx>>3)&63;
        int j    = idx&7;
        int oc = og*32 + (lane&31);
        int c  = kc*16 + (lane>>5)*8 + j;
        int grp = oc>>4, oo = oc&15; int K = (grp&1)?7:5;
        const float* w = (grp==0)?rk5w:(grp==1)?rk7w:(grp==2)?lk5w:lk7w;
        float s = 0.f;
        for(int k=0;k<K;k++) s += w[(oo*K+k)*64 + c];
        fuwf[idx] = f2bfu(s);
    }
    unsigned short* fcwf = (unsigned short*)(ws + FCWf);
    for(int idx=tid; idx<4096; idx+=nt){
        int og   = idx>>11;
        int kc   = (idx>>9)&3;
        int lane = (idx>>3)&63;
        int j    = idx&7;
        int oc = og*32 + (lane&31);
        int c  = kc*16 + (lane>>5)*8 + j;
        fcwf[idx] = f2bfu(fcw[oc*64 + c]);
    }
}

// ============ K1: x (fp32 NCHW) -> XB (bf16 NHWC) — R1 verbatim ============
__global__ __launch_bounds__(256)
void k_x2nhwc(const float* __restrict__ x, unsigned short* __restrict__ xb)
{
    __shared__ unsigned short ls[128*72];
    const int t = threadIdx.x;
    const int p0 = blockIdx.x*128;
    const int b = p0 / HWs, pp0 = p0 % HWs;
    const float4* xb4 = (const float4*)(x + (size_t)b*CC*HWs + pp0);
    #pragma unroll
    for(int iter=0; iter<8; iter++){
        int idx = iter*256 + t;
        int c = idx>>5, g = idx&31;
        float4 v = xb4[(size_t)c*(HWs/4) + g];
        int px = g*4;
        int bs = (c>>3) ^ ((g>>1)&7);
        unsigned short* base = ls + bs*8 + (c&7);
        base[(px+0)*72] = f2bfu(v.x);
        base[(px+1)*72] = f2bfu(v.y);
        base[(px+2)*72] = f2bfu(v.z);
        base[(px+3)*72] = f2bfu(v.w);
    }
    __syncthreads();
    #pragma unroll
    for(int iter=0; iter<4; iter++){
        int idx = iter*256 + t;
        int sub = idx&7, px = idx>>3;
        int bs = sub ^ ((px>>3)&7);
        short8v v = *(short8v*)(ls + px*72 + bs*8);
        *(short8v*)(xb + ((size_t)(p0+px))*64 + sub*8) = v;
    }
}

// ====== K2 (R6 structure, R7: 512 threads / 8 waves for latency hiding) ======
// x-tile 20x12 (halo 2), FUS 18x10 in LDS, out 16x8.
// B: waves 0-5 one attn px-tile each. C: sobel 1 item/thread (i=511-t).
// D: wave w -> tile w, both og. E: og split across wave pairs, yb via LDS.
__global__ __launch_bounds__(512, 4)
void k_fuse(const unsigned short* __restrict__ xb, const float* __restrict__ bab1,
            const float* __restrict__ baw2, const float* __restrict__ bab2,
            const float* __restrict__ ws, const float* __restrict__ fcb,
            const float* __restrict__ x, float* __restrict__ out)
{
    __shared__ unsigned short xt[240*72];     // 34,560 B (aliased as yb-exchange in E)
    __shared__ unsigned short ftile[180*72];  // 25,920 B
    __shared__ float ebuf[2][180];
    const int bw = blockIdx.x, bh = blockIdx.y, b = blockIdx.z;
    const int t = threadIdx.x;
    const int wave = t>>6, lane = t&63;
    const int half = lane>>5, n = lane&31;
    const int w0 = bw*16, h0 = bh*8;

    // --- stage x tile (halo 2) from XB, zero-filled OOB ---
    const unsigned short* fb = xb + (size_t)b*HWs*64;
    for(int idx=t; idx<1920; idx+=512){
        int sub = idx&7; int pix = idx>>3;
        int r = pix/20, c = pix - r*20;
        int gh = h0-2+r, gw = w0-2+c;
        short8v v = {0,0,0,0,0,0,0,0};
        if(gh>=0&&gh<HH&&gw>=0&&gw<WW)
            v = *(const short8v*)(fb + ((size_t)(gh*WW+gw))*64 + sub*8);
        *(short8v*)(xt + pix*72 + sub*8) = v;
    }
    __syncthreads();

    // --- phase B: attn conv + colsum, waves 0-5, one tile each ---
    float cz = 0.f, sx = 0.f;
    if(wave < 6){
        int p = wave*32 + n; if(p > 179) p = 179;
        int pr = p/18, pc = p - pr*18;
        const unsigned short* bawf = (const unsigned short*)(ws + BAWf);
        float16v acc = fzero16();
        #pragma unroll
        for(int kc=0; kc<4; kc++){
            short8v af[9];
            #pragma unroll
            for(int tap=0; tap<9; tap++)
                af[tap] = *(const short8v*)(bawf + (((size_t)(tap*4+kc))*64 + lane)*8);
            #pragma unroll
            for(int tap=0; tap<9; tap++){
                const int dh = tap/3, dw = tap%3;
                short8v bf = *(const short8v*)(xt + ((pr+dh)*20 + pc+dw)*72
                                               + kc*16 + half*8);
                acc = __builtin_amdgcn_mfma_f32_32x32x16_bf16(af[tap], bf, acc, 0,0,0);
            }
        }
        #pragma unroll
        for(int r=0;r<16;r++){
            int oc = (r&3) + 8*(r>>2) + 4*half;
            cz += fmaxf(acc[r]+bab1[oc],0.f)*baw2[oc];
        }
        cz += __shfl_xor(cz, 32);
        short8v ones;
        #pragma unroll
        for(int j=0;j<8;j++) ones[j] = (short)0x3F80;
        float16v s = fzero16();
        #pragma unroll
        for(int kc=0; kc<4; kc++){
            short8v bf = *(const short8v*)(xt + ((pr+1)*20 + pc+1)*72 + kc*16 + half*8);
            s = __builtin_amdgcn_mfma_f32_32x32x16_bf16(ones, bf, s, 0,0,0);
        }
        sx = s[0];
    }
    // --- phase C: sobel, 1 item/thread; waves 6-7 take items 0-127 first ---
    {
        const int i2 = 511 - t;
        if(i2 < 360){
            const int hf = (i2>=180) ? 1 : 0;
            const int px2 = i2 - hf*180;
            const int r = px2/18, c = px2 - (px2/18)*18;
            float e = 0.f;
            #pragma unroll
            for(int s=0; s<4; s++){
                const int sub = hf*4 + s;
                if(hf==0){
                    short8v a0 = *(const short8v*)(xt + ((r  )*20 + c  )*72 + sub*8);
                    short8v a2 = *(const short8v*)(xt + ((r  )*20 + c+2)*72 + sub*8);
                    short8v a3 = *(const short8v*)(xt + ((r+1)*20 + c  )*72 + sub*8);
                    short8v a5 = *(const short8v*)(xt + ((r+1)*20 + c+2)*72 + sub*8);
                    short8v a6 = *(const short8v*)(xt + ((r+2)*20 + c  )*72 + sub*8);
                    short8v a8 = *(const short8v*)(xt + ((r+2)*20 + c+2)*72 + sub*8);
                    #pragma unroll
                    for(int j=0;j<8;j++){
                        float gx = (bfu2f((unsigned short)a2[j]) - bfu2f((unsigned short)a0[j]))
                           + 2.f*(bfu2f((unsigned short)a5[j]) - bfu2f((unsigned short)a3[j]))
                           +      (bfu2f((unsigned short)a8[j]) - bfu2f((unsigned short)a6[j]));
                        e += fabsf(gx);
                    }
                } else {
                    short8v b0 = *(const short8v*)(xt + ((r  )*20 + c  )*72 + sub*8);
                    short8v b1 = *(const short8v*)(xt + ((r  )*20 + c+1)*72 + sub*8);
                    short8v b2 = *(const short8v*)(xt + ((r  )*20 + c+2)*72 + sub*8);
                    short8v b6 = *(const short8v*)(xt + ((r+2)*20 + c  )*72 + sub*8);
                    short8v b7 = *(const short8v*)(xt + ((r+2)*20 + c+1)*72 + sub*8);
                    short8v b8 = *(const short8v*)(xt + ((r+2)*20 + c+2)*72 + sub*8);
                    #pragma unroll
                    for(int j=0;j<8;j++){
                        float gy = (bfu2f((unsigned short)b6[j]) - bfu2f((unsigned short)b0[j]))
                           + 2.f*(bfu2f((unsigned short)b7[j]) - bfu2f((unsigned short)b1[j]))
                           +      (bfu2f((unsigned short)b2[j]) - bfu2f((unsigned short)b2[j]))*0.f
                           +      (bfu2f((unsigned short)b8[j]) - bfu2f((unsigned short)b2[j]));
                        e += fabsf(gy);
                    }
                }
            }
            ebuf[hf][px2] = e;
        }
    }
    __syncthreads();

    // --- phase D: sigmoid scalars + dyn1d -> ftile, waves 0-5 ---
    if(wave < 6){
        const unsigned short* fuwf = (const unsigned short*)(ws + FUWf);
        int p0g = wave*32 + n;
        bool wr = (p0g < 180);
        int p = wr ? p0g : 179;
        int pr = p/18, pc = p - pr*18;
        float z = cz + bab2[0] + (ebuf[0][p] + ebuf[1][p]) * (1.f/32.f);
        float A = 1.f + 1.f/(1.f+__expf(-z));
        float Q = A * sx;
        float P = A * Q;
        #pragma unroll
        for(int og=0; og<2; og++){
            float16v a = fzero16();
            #pragma unroll
            for(int kc=0; kc<4; kc++){
                short8v wf = *(const short8v*)(fuwf + (((size_t)og*4 + kc)*64 + lane)*8);
                short8v bf = *(const short8v*)(xt + ((pr+1)*20 + pc+1)*72 + kc*16 + half*8);
                a = __builtin_amdgcn_mfma_f32_32x32x16_bf16(wf, bf, a, 0,0,0);
            }
            float bq[16];
            #pragma unroll
            for(int r=0;r<16;r++) bq[r] = ws[B1X1 + og*32 + (r&3)+8*(r>>2)+4*half];
            unsigned short* base = ftile + p*72 + og*32 + 4*half;
            #pragma unroll
            for(int gq=0; gq<4; gq++){
                union { unsigned long long u; unsigned short s[4]; } pk;
                #pragma unroll
                for(int rr=0; rr<4; rr++)
                    pk.s[rr] = f2bfu(P*a[4*gq+rr] + Q*bq[4*gq+rr]);
                if(wr) *(unsigned long long*)(base + 8*gq) = pk.u;
            }
        }
    }
    __syncthreads();

    // --- phase E: sf conv (og = wave>>2) + fc (og0 waves) + residual ---
    const int rp  = wave & 3;
    const int og  = wave >> 2;
    const int row = 2*rp + (n>>4), col = n&15;
    const unsigned short* sfwf = (const unsigned short*)(ws + SFWf);
    const unsigned short* fcwf = (const unsigned short*)(ws + FCWf);

    float16v Y = fzero16();
    #pragma unroll
    for(int kc=0; kc<4; kc++){
        short8v af[9];
        #pragma unroll
        for(int tap=0; tap<9; tap++)
            af[tap] = *(const short8v*)(sfwf + (((size_t)og*36 + tap*4+kc)*64 + lane)*8);
        #pragma unroll
        for(int tap=0; tap<9; tap++){
            const int dh = tap/3, dw = tap%3;
            short8v bf = *(const short8v*)(ftile + ((row+dh)*18 + col+dw)*72
                                           + kc*16 + half*8);
            Y = __builtin_amdgcn_mfma_f32_32x32x16_bf16(af[tap], bf, Y, 0,0,0);
        }
    }
    unsigned short yb[16];
    #pragma unroll
    for(int r=0;r<16;r++){
        float bias = ws[SFBo + og*32 + (r&3)+8*(r>>2)+4*half];
        yb[r] = f2bfu(fmaxf(Y[r] + bias, 0.f));
    }
    unsigned long long* ybx64 = (unsigned long long*)xt;   // xt dead after D
    if(og==1){
        #pragma unroll
        for(int q=0;q<4;q++){
            union { unsigned long long u; unsigned short s[4]; } pk;
            #pragma unroll
            for(int rr=0;rr<4;rr++) pk.s[rr] = yb[4*q+rr];
            ybx64[((size_t)rp*64 + lane)*4 + q] = pk.u;
        }
    }
    __syncthreads();
    if(og==0){
        float16v F0 = fzero16(), F1 = fzero16();
        // kc_fc = 0,1 : own og0 yb + shfl exchange (R1 path)
        #pragma unroll
        for(int kcl=0; kcl<2; kcl++){
            unsigned short l0,l1,l2,l3, s0,s1,s2,s3;
            if(half==0){ l0=yb[8*kcl+0]; l1=yb[8*kcl+1]; l2=yb[8*kcl+2]; l3=yb[8*kcl+3];
                         s0=yb[8*kcl+4]; s1=yb[8*kcl+5]; s2=yb[8*kcl+6]; s3=yb[8*kcl+7]; }
            else       { l0=yb[8*kcl+4]; l1=yb[8*kcl+5]; l2=yb[8*kcl+6]; l3=yb[8*kcl+7];
                         s0=yb[8*kcl+0]; s1=yb[8*kcl+1]; s2=yb[8*kcl+2]; s3=yb[8*kcl+3]; }
            int p0 = (int)((unsigned)s0 | ((unsigned)s1<<16));
            int p1 = (int)((unsigned)s2 | ((unsigned)s3<<16));
            int r0 = __shfl_xor(p0, 32);
            int r1 = __shfl_xor(p1, 32);
            unsigned short m0 = (unsigned short)(r0 & 0xffff);
            unsigned short m1 = (unsigned short)(((unsigned)r0) >> 16);
            unsigned short m2 = (unsigned short)(r1 & 0xffff);
            unsigned short m3 = (unsigned short)(((unsigned)r1) >> 16);
            short8v B;
            if(half==0){ B[0]=(short)l0; B[1]=(short)l1; B[2]=(short)l2; B[3]=(short)l3;
                         B[4]=(short)m0; B[5]=(short)m1; B[6]=(short)m2; B[7]=(short)m3; }
            else       { B[0]=(short)m0; B[1]=(short)m1; B[2]=(short)m2; B[3]=(short)m3;
                         B[4]=(short)l0; B[5]=(short)l1; B[6]=(short)l2; B[7]=(short)l3; }
            short8v fa0 = *(const short8v*)(fcwf + (((size_t)0*4 + kcl)*64 + lane)*8);
            short8v fa1 = *(const short8v*)(fcwf + (((size_t)1*4 + kcl)*64 + lane)*8);
            F0 = __builtin_amdgcn_mfma_f32_32x32x16_bf16(fa0, B, F0, 0,0,0);
            F1 = __builtin_amdgcn_mfma_f32_32x32x16_bf16(fa1, B, F1, 0,0,0);
        }
        // kc_fc = 2,3 : og1 yb from LDS (partner wave rp slot)
        #pragma unroll
        for(int kcl=0; kcl<2; kcl++){
            const int kc_fc = 2 + kcl;
            const int gsel  = 2*kcl + half;
            const int srcA  = half ? (lane^32) : lane;
            const int srcB  = half ? lane : (lane^32);
            unsigned long long a03 = ybx64[((size_t)rp*64 + srcA)*4 + gsel];
            unsigned long long a47 = ybx64[((size_t)rp*64 + srcB)*4 + gsel];
            short8v B;
            #pragma unroll
            for(int j2=0;j2<4;j2++){
                B[j2]   = (short)(unsigned short)((a03 >> (16*j2)) & 0xffff);
                B[4+j2] = (short)(unsigned short)((a47 >> (16*j2)) & 0xffff);
            }
            short8v fa0 = *(const short8v*)(fcwf + (((size_t)0*4 + kc_fc)*64 + lane)*8);
            short8v fa1 = *(const short8v*)(fcwf + (((size_t)1*4 + kc_fc)*64 + lane)*8);
            F0 = __builtin_amdgcn_mfma_f32_32x32x16_bf16(fa0, B, F0, 0,0,0);
            F1 = __builtin_amdgcn_mfma_f32_32x32x16_bf16(fa1, B, F1, 0,0,0);
        }
        // epilogue: bias + residual -> fp32 NCHW out
        #pragma unroll
        for(int og2=0; og2<2; og2++){
            #pragma unroll
            for(int r=0;r<16;r++){
                int oc = og2*32 + (r&3)+8*(r>>2)+4*half;
                size_t g = ((size_t)(b*CC + oc))*HWs + (h0+row)*WW + w0 + col;
                float v = (og2==0) ? F0[r] : F1[r];
                out[g] = v + fcb[oc] + x[g];
            }
        }
    }
}

extern "C" void kernel_launch(void* const* d_in, const int* in_sizes, int n_in,
                              void* d_out, int out_size, void* d_ws, size_t ws_size,
                              hipStream_t stream)
{
    const float* x     = (const float*)d_in[0];
    const float* ba_w1 = (const float*)d_in[1];
    const float* ba_b1 = (const float*)d_in[2];
    const float* ba_w2 = (const float*)d_in[3];
    const float* ba_b2 = (const float*)d_in[4];
    const float* rk5_w = (const float*)d_in[13];
    const float* rk5_b = (const float*)d_in[14];
    const float* rk7_w = (const float*)d_in[15];
    const float* rk7_b = (const float*)d_in[16];
    const float* lk5_w = (const float*)d_in[17];
    const float* lk5_b = (const float*)d_in[18];
    const float* lk7_w = (const float*)d_in[19];
    const float* lk7_b = (const float*)d_in[20];
    const float* sf_w  = (const float*)d_in[21];
    const float* sf_b  = (const float*)d_in[22];
    const float* bng   = (const float*)d_in[23];
    const float* bnb   = (const float*)d_in[24];
    const float* bnm   = (const float*)d_in[25];
    const float* bnv   = (const float*)d_in[26];
    const float* fc_w  = (const float*)d_in[27];
    const float* fc_b  = (const float*)d_in[28];

    float* wsf = (float*)d_ws;
    unsigned short* XB  = (unsigned short*)((char*)d_ws + (size_t)WS_FLOATS*4);
    float* out = (float*)d_out;

    k_prep<<<64, 256, 0, stream>>>(rk5_w,rk5_b,rk7_w,rk7_b,lk5_w,lk5_b,lk7_w,lk7_b,
                                   sf_w,sf_b,bng,bnb,bnm,bnv, ba_w1, fc_w, wsf);
    k_x2nhwc<<<NPIX/128, 256, 0, stream>>>(x, XB);
    k_fuse<<<dim3(10,20,4), 512, 0, stream>>>(XB, ba_b1, ba_w2, ba_b2, wsf, fc_b, x, out);
}